// Round 8
// baseline (437.663 us; speedup 1.0000x reference)
//
#include <hip/hip_runtime.h>
#include <stdint.h>

#define N_B 32
#define C_D 256
#define T_D 1024
#define QB 32

typedef unsigned short u16;
typedef __attribute__((ext_vector_type(8))) short short8;
typedef __attribute__((ext_vector_type(4))) float f32x4;

__device__ __forceinline__ u16 f2bf(float f) {
    unsigned x = __float_as_uint(f);
    return (u16)((x + 0x7fffu + ((x >> 16) & 1u)) >> 16);  // RNE
}

__device__ __forceinline__ void gld16(const void* g, void* l) {
    __builtin_amdgcn_global_load_lds(
        (const __attribute__((address_space(1))) uint32_t*)g,
        (__attribute__((address_space(3))) uint32_t*)l, 16, 0, 0);
}

// fast tanh: 1 - 2/(e^{2x}+1). exp->inf gives 1, exp->0 gives -1 (exact limits).
__device__ __forceinline__ float ftanh(float x) {
    float t = __expf(2.0f * x);
    return 1.0f - 2.0f * __builtin_amdgcn_rcpf(t + 1.0f);
}

// flash-style (m,l) merge
__device__ __forceinline__ void comb(float& m, float& l, float m2, float l2) {
    float M = fmaxf(m, m2);
    l = l * __expf(m - M) + l2 * __expf(m2 - M);
    m = M;
}

// ---- weights: 3x (256x256) fp32 -> bf16, one launch ----
__global__ __launch_bounds__(256) void conv_w(const float* __restrict__ w0,
                                              const float* __restrict__ w1,
                                              const float* __restrict__ w2,
                                              u16* __restrict__ o0,
                                              u16* __restrict__ o1,
                                              u16* __restrict__ o2) {
    const float* in = blockIdx.y == 0 ? w0 : (blockIdx.y == 1 ? w1 : w2);
    u16* out       = blockIdx.y == 0 ? o0 : (blockIdx.y == 1 ? o1 : o2);
    int i = blockIdx.x * 256 + threadIdx.x;
    out[i] = f2bf(in[i]);
}

// ---- staged transpose+convert: fp32 k-major source (row stride T_D) -> LDS
// [cols][32 k] bf16 tile, XOR-swizzled (chunk ^ ((t>>4)&3)<<3).
__device__ __forceinline__ void stage_tr(const float* __restrict__ src,
                                         u16* __restrict__ sm,
                                         int sr2, int tt8) {
    float4 v0 = *(const float4*)(src);
    float4 v1 = *(const float4*)(src + 4);
    float4 w0 = *(const float4*)(src + T_D);
    float4 w1 = *(const float4*)(src + T_D + 4);
    float a[8] = {v0.x, v0.y, v0.z, v0.w, v1.x, v1.y, v1.z, v1.w};
    float b[8] = {w0.x, w0.y, w0.z, w0.w, w1.x, w1.y, w1.z, w1.w};
    const int kk = sr2 * 2;
#pragma unroll
    for (int j = 0; j < 8; ++j) {
        const int t  = tt8 + j;
        const int ks = kk ^ (((t >> 4) & 3) << 3);
        uint32_t pk = (uint32_t)f2bf(a[j]) | ((uint32_t)f2bf(b[j]) << 16);
        *(uint32_t*)(sm + t * 32 + ks) = pk;
    }
}

// --------- unified GEMM: Out[m,n] = epi(scale * sum_k A[m,k]*B[n,k]) -------
// TRA/TRB: that side is fp32 k-major (row stride T_D), transposed+converted
// at staging. Otherwise bf16 rows K-contig (stride Kdim), gld16-staged with
// SOURCE-swizzled chunks so fragment ds_read_b128 is 2-way (free).
// EPI: 1 = tanh(x + bias[n]); 2 = tanh(x + bias[m])
// DUAL: blockIdx.z in [N_B,2*N_B) uses the second operand set (Q+K merge).
template <bool TRA, bool TRB, int EPI, bool DUAL>
__global__ __launch_bounds__(256) void gemm_t(
        const void* __restrict__ Av, const void* __restrict__ Bv,
        const float* __restrict__ bias, void* __restrict__ OutV,
        int Kdim, int ldo, long sA, long sB, long sO, float scale,
        const void* __restrict__ Av2, const void* __restrict__ Bv2,
        const float* __restrict__ bias2, void* __restrict__ Out2)
{
    __shared__ __align__(16) u16 smA[128 * 32];
    __shared__ __align__(16) u16 smB[128 * 32];

    int nb = blockIdx.z;
    if (DUAL && nb >= N_B) {
        nb -= N_B;
        Av = Av2; Bv = Bv2; bias = bias2; OutV = Out2;
    }
    const int n0 = blockIdx.x * 128;
    const int m0 = blockIdx.y * 128;
    const int tid = threadIdx.x;

    const int srow = tid >> 2;
    const int sk8  = (((tid & 3) ^ ((srow >> 1) & 3)) * 8);  // src-swizzled
    const int sr2  = tid >> 4;
    const int tt8  = (tid & 15) * 8;

    const u16* gA0 = nullptr; const u16* gA1 = nullptr;
    const float* tA = nullptr;
    if constexpr (TRA) {
        tA = (const float*)Av + (size_t)nb * sA + (size_t)(sr2 * 2) * T_D + m0 + tt8;
    } else {
        const u16* Ab = (const u16*)Av + (size_t)nb * sA;
        gA0 = Ab + (size_t)(m0 + srow) * Kdim + sk8;
        gA1 = gA0 + (size_t)64 * Kdim;
    }
    const u16* gB0 = nullptr; const u16* gB1 = nullptr;
    const float* tB = nullptr;
    if constexpr (TRB) {
        tB = (const float*)Bv + (size_t)nb * sB + (size_t)(sr2 * 2) * T_D + n0 + tt8;
    } else {
        const u16* Bb = (const u16*)Bv + (size_t)nb * sB;
        gB0 = Bb + (size_t)(n0 + srow) * Kdim + sk8;
        gB1 = gB0 + (size_t)64 * Kdim;
    }
    u16* lA0 = smA + tid * 8; u16* lA1 = smA + 2048 + tid * 8;
    u16* lB0 = smB + tid * 8; u16* lB1 = smB + 2048 + tid * 8;

    const int lane = tid & 63;
    const int w    = tid >> 6;
    const int wm   = (w >> 1) * 64;
    const int wn   = (w & 1) * 64;
    const int l15  = lane & 15;
    const int quad = lane >> 4;

    f32x4 acc[4][4];
#pragma unroll
    for (int i = 0; i < 4; ++i)
#pragma unroll
        for (int j = 0; j < 4; ++j) acc[i][j] = (f32x4){0.f, 0.f, 0.f, 0.f};

    for (int kb = 0; kb < Kdim; kb += 32) {
        if constexpr (TRA) {
            stage_tr(tA + (size_t)kb * T_D, smA, sr2, tt8);
        } else {
            gld16(gA0 + kb, lA0);
            gld16(gA1 + kb, lA1);
        }
        if constexpr (TRB) {
            stage_tr(tB + (size_t)kb * T_D, smB, sr2, tt8);
        } else {
            gld16(gB0 + kb, lB0);
            gld16(gB1 + kb, lB1);
        }
        __syncthreads();
        short8 af[4], bfr[4];
#pragma unroll
        for (int i = 0; i < 4; ++i) {
            const int ra = wm + i * 16 + l15;
            const int ca = TRA ? ((quad ^ ((ra >> 4) & 3)) * 8)
                               : ((quad ^ ((ra >> 1) & 3)) * 8);
            af[i] = *(const short8*)(smA + ra * 32 + ca);
            const int rb = wn + i * 16 + l15;
            const int cb = TRB ? ((quad ^ ((rb >> 4) & 3)) * 8)
                               : ((quad ^ ((rb >> 1) & 3)) * 8);
            bfr[i] = *(const short8*)(smB + rb * 32 + cb);
        }
#pragma unroll
        for (int mi = 0; mi < 4; ++mi)
#pragma unroll
            for (int ni = 0; ni < 4; ++ni)
                acc[mi][ni] = __builtin_amdgcn_mfma_f32_16x16x32_bf16(
                        af[mi], bfr[ni], acc[mi][ni], 0, 0, 0);
        __syncthreads();
    }

#pragma unroll
    for (int mi = 0; mi < 4; ++mi) {
        const int mb = m0 + wm + mi * 16 + quad * 4;
#pragma unroll
        for (int r = 0; r < 4; ++r) {
            const int m = mb + r;
            float bm = 0.f;
            if (EPI == 2) bm = bias[m];
#pragma unroll
            for (int ni = 0; ni < 4; ++ni) {
                const int nn = n0 + wn + ni * 16 + l15;
                float v = acc[mi][ni][r] * scale;
                if (EPI == 1) v = ftanh(v + bias[nn]);
                if (EPI == 2) v = ftanh(v + bm);
                ((u16*)OutV)[(size_t)nb * sO + (size_t)m * ldo + nn] = f2bf(v);
            }
        }
    }
}

// ===================== fused scores+softmax+PV kernel =====================
// One block per (nb, 32-wide t-panel). 512 thr / 8 waves, 80 KB LDS.
// Phase 1: S(s,t-panel) = Kp.Qp^T / 16 into registers (acc[8][2]); K staged
//   via REGISTER PREFETCH (half-kb granularity): next half's global loads are
//   in flight while this half's MFMAs run. No barrier in the K-loop.
// Softmax over s fully on-chip -> M[t], 1/L[t].
// Normalize writes fp32 A (only HBM trip for S) + packs bf16 P into LDS.
// Phase 2: R(c,t) = Vp . P with 2-deep register prefetch (pvA/pvB).
// NOTE: `red` aliases smQ — written only after the post-phase-1 barrier.
__global__ __launch_bounds__(512, 4) void attn_fused(
        const u16* __restrict__ Kp,   // (n,s,c) bf16
        const u16* __restrict__ Qp,   // (n,t,c) bf16
        const u16* __restrict__ Vp,   // (n,c,s) bf16
        float* __restrict__ A,        // (n,s,t) fp32 out
        float* __restrict__ Rr)       // (n,c,t) fp32 out (scratch home)
{
    __shared__ __align__(16) u16 lds[40960];   // 80 KB
    u16* smK = lds;                  // p1: [1024 s][4 slot(8c)]  64 KB (wave-priv)
    u16* smQ = lds + 32768;          // p1: [32 t][32 slot(8c)]   16 KB (shared)
    u16* smP = lds;                  // p2: [32 t][128 slot8(8s)] 64 KB (shared)
    u16* smV = lds + 32768;          // p2: [256 c][4 slot(8s)]   16 KB (wave-priv)
    float* red = (float*)(lds + 32768);  // softmax scratch (smQ dead by then)

    const int bid = blockIdx.x;
    const int idx = (bid & 7) * 128 + (bid >> 3);   // XCD-contiguous remap
    const int nb  = idx >> 5;
    const int t0  = (idx & 31) * QB;

    const int tid  = threadIdx.x;
    const int lane = tid & 63;
    const int w    = tid >> 6;
    const int l15  = lane & 15;
    const int quad = lane >> 4;

    const u16* Kb = Kp + (size_t)nb * (T_D * C_D);
    const u16* Qb = Qp + (size_t)nb * (T_D * C_D);
    const u16* Vb = Vp + (size_t)nb * (C_D * T_D);
    float* Ab = A + (size_t)nb * ((size_t)T_D * T_D) + t0;
    float* Rb = Rr + (size_t)nb * (C_D * T_D) + t0;

    // ---- stage Qp panel (block-shared, source-swizzled) ----
    {
        const int tq   = tid >> 5;      // 0..15
        const int slot = tid & 31;
#pragma unroll
        for (int c = 0; c < 2; ++c) {
            const int tt = c * 16 + tq;
            const int chunk = slot ^ (tt & 7);
            gld16(Qb + (size_t)(t0 + tt) * C_D + chunk * 8,
                  smQ + c * 4096 + tid * 8);
        }
    }

    f32x4 acc[8][2];
#pragma unroll
    for (int i = 0; i < 8; ++i)
#pragma unroll
        for (int j = 0; j < 2; ++j) acc[i][j] = (f32x4){0.f, 0.f, 0.f, 0.f};

    __syncthreads();   // smQ ready (vmcnt drained at barrier)

    // ---- phase 1: wave w owns s-rows [w*128,(w+1)*128), barrier-free ----
    u16* smKw = smK + w * 4096;                       // 8 KB wave region
    const u16* Kw = Kb + (size_t)(w * 128) * C_D;

    uint4 pf[4];
    auto ldKh = [&](int kb, int h) {
#pragma unroll
        for (int c = 0; c < 4; ++c) {
            const int cc = h * 4 + c;
            const int s  = cc * 16 + (lane >> 2);
            const int ck = (lane & 3) ^ ((s >> 1) & 3);
            pf[c] = *(const uint4*)(Kw + (size_t)s * C_D + kb * 32 + ck * 8);
        }
    };

    ldKh(0, 0);
    for (int kb = 0; kb < 8; ++kb) {
        short8 bq0, bq1;
        // half 0: c-blocks 0..3 (next half's loads fly under the MFMAs)
        {
#pragma unroll
            for (int c = 0; c < 4; ++c)
                *(uint4*)(smKw + c * 512 + lane * 8) = pf[c];
            ldKh(kb, 1);
            bq0 = *(const short8*)(smQ + l15 * 256 +
                                   (((kb * 4 + quad) ^ (l15 & 7)) * 8));
            bq1 = *(const short8*)(smQ + (16 + l15) * 256 +
                                   (((kb * 4 + quad) ^ (l15 & 7)) * 8));
#pragma unroll
            for (int i = 0; i < 4; ++i) {
                const int sl = i * 16 + l15;
                short8 af = *(const short8*)(smKw + sl * 32 +
                                             ((quad ^ ((sl >> 1) & 3)) * 8));
                acc[i][0] = __builtin_amdgcn_mfma_f32_16x16x32_bf16(af, bq0, acc[i][0], 0, 0, 0);
                acc[i][1] = __builtin_amdgcn_mfma_f32_16x16x32_bf16(af, bq1, acc[i][1], 0, 0, 0);
            }
        }
        // half 1: c-blocks 4..7
        {
#pragma unroll
            for (int c = 0; c < 4; ++c)
                *(uint4*)(smKw + (4 + c) * 512 + lane * 8) = pf[c];
            if (kb < 7) ldKh(kb + 1, 0);
#pragma unroll
            for (int i = 4; i < 8; ++i) {
                const int sl = i * 16 + l15;
                short8 af = *(const short8*)(smKw + sl * 32 +
                                             ((quad ^ ((sl >> 1) & 3)) * 8));
                acc[i][0] = __builtin_amdgcn_mfma_f32_16x16x32_bf16(af, bq0, acc[i][0], 0, 0, 0);
                acc[i][1] = __builtin_amdgcn_mfma_f32_16x16x32_bf16(af, bq1, acc[i][1], 0, 0, 0);
            }
        }
    }

    // ---- softmax over s: per-thread -> quad shfl -> 8-wave LDS merge ----
    float pm2[2], pl2[2];
#pragma unroll
    for (int ni = 0; ni < 2; ++ni) {
        float m = -1e30f;
#pragma unroll
        for (int mi = 0; mi < 8; ++mi)
#pragma unroll
            for (int r = 0; r < 4; ++r)
                m = fmaxf(m, acc[mi][ni][r] * 0.0625f);
        float l = 0.f;
#pragma unroll
        for (int mi = 0; mi < 8; ++mi)
#pragma unroll
            for (int r = 0; r < 4; ++r)
                l += __expf(acc[mi][ni][r] * 0.0625f - m);
        float m2 = __shfl_xor(m, 16), l2 = __shfl_xor(l, 16);
        comb(m, l, m2, l2);
        m2 = __shfl_xor(m, 32); l2 = __shfl_xor(l, 32);
        comb(m, l, m2, l2);
        pm2[ni] = m; pl2[ni] = l;
    }

    __syncthreads();   // ALL waves done with phase 1 (smQ/smK reads) —
                       // only now is `red` (aliasing smQ) safe to write.

    float* pmL = red;            // [8][32]
    float* plL = red + 256;
    float* fM  = red + 512;      // [32]
    float* fR  = red + 544;
    if (quad == 0) {
#pragma unroll
        for (int ni = 0; ni < 2; ++ni) {
            pmL[w * 32 + ni * 16 + l15] = pm2[ni];
            plL[w * 32 + ni * 16 + l15] = pl2[ni];
        }
    }
    __syncthreads();
    if (tid < 32) {
        float M = -1e30f;
#pragma unroll
        for (int j = 0; j < 8; ++j) M = fmaxf(M, pmL[j * 32 + tid]);
        float L = 0.f;
#pragma unroll
        for (int j = 0; j < 8; ++j)
            L += plL[j * 32 + tid] * __expf(pmL[j * 32 + tid] - M);
        fM[tid] = M;
        fR[tid] = 1.0f / L;
    }
    __syncthreads();
    float Mn[2], Rn[2];
#pragma unroll
    for (int ni = 0; ni < 2; ++ni) {
        Mn[ni] = fM[ni * 16 + l15];
        Rn[ni] = fR[ni * 16 + l15];
    }

    // ---- normalize: write fp32 A + pack bf16 P into LDS (swizzled) ----
#pragma unroll
    for (int mi = 0; mi < 8; ++mi) {
        const int sbase = w * 128 + mi * 16 + quad * 4;
        const int c4    = w * 32 + mi * 4 + quad;    // s-quartet index
        const int slot8 = c4 >> 1;
        const int half  = c4 & 1;
#pragma unroll
        for (int ni = 0; ni < 2; ++ni) {
            const int t = ni * 16 + l15;
            float a0 = __expf(acc[mi][ni][0] * 0.0625f - Mn[ni]) * Rn[ni];
            float a1 = __expf(acc[mi][ni][1] * 0.0625f - Mn[ni]) * Rn[ni];
            float a2 = __expf(acc[mi][ni][2] * 0.0625f - Mn[ni]) * Rn[ni];
            float a3 = __expf(acc[mi][ni][3] * 0.0625f - Mn[ni]) * Rn[ni];
            Ab[(size_t)(sbase + 0) * T_D + t] = a0;
            Ab[(size_t)(sbase + 1) * T_D + t] = a1;
            Ab[(size_t)(sbase + 2) * T_D + t] = a2;
            Ab[(size_t)(sbase + 3) * T_D + t] = a3;
            uint2 pk;
            pk.x = (uint32_t)f2bf(a0) | ((uint32_t)f2bf(a1) << 16);
            pk.y = (uint32_t)f2bf(a2) | ((uint32_t)f2bf(a3) << 16);
            *(uint2*)(smP + t * 1024 + (slot8 ^ (t & 7)) * 8 + half * 4) = pk;
        }
    }
    __syncthreads();   // P complete; fM/fR consumed; smV region free

    // ---- phase 2: R = Vp . P; wave w owns c-rows [w*32,(w+1)*32);
    //      2-deep register prefetch (pvA/pvB), barrier-free ----
    f32x4 acc2[2][2];
#pragma unroll
    for (int i = 0; i < 2; ++i)
#pragma unroll
        for (int j = 0; j < 2; ++j) acc2[i][j] = (f32x4){0.f, 0.f, 0.f, 0.f};

    u16* smVw = smV + w * 1024;                     // 2 KB wave region
    uint4 pvA[2], pvB[2];
    auto ldV = [&](uint4* d, int kb) {
#pragma unroll
        for (int c = 0; c < 2; ++c) {
            const int cc = w * 32 + c * 16 + (lane >> 2);
            const int ck = (lane & 3) ^ ((cc >> 1) & 3);
            d[c] = *(const uint4*)(Vb + (size_t)cc * T_D + kb * 32 + ck * 8);
        }
    };
    ldV(pvA, 0);
    ldV(pvB, 1);
    for (int kb = 0; kb < 32; kb += 2) {
        // even sub-step (pvA)
        {
            *(uint4*)(smVw + lane * 8)       = pvA[0];
            *(uint4*)(smVw + 512 + lane * 8) = pvA[1];
            if (kb + 2 < 32) ldV(pvA, kb + 2);
            const int cc0 = w * 32 + l15;
            const int cc1 = w * 32 + 16 + l15;
            short8 av0 = *(const short8*)(smV + cc0 * 32 + ((quad ^ ((cc0 >> 1) & 3)) * 8));
            short8 av1 = *(const short8*)(smV + cc1 * 32 + ((quad ^ ((cc1 >> 1) & 3)) * 8));
            short8 pb0 = *(const short8*)(smP + l15 * 1024 + (((kb * 4 + quad) ^ (l15 & 7)) * 8));
            short8 pb1 = *(const short8*)(smP + (16 + l15) * 1024 + (((kb * 4 + quad) ^ (l15 & 7)) * 8));
            acc2[0][0] = __builtin_amdgcn_mfma_f32_16x16x32_bf16(av0, pb0, acc2[0][0], 0, 0, 0);
            acc2[0][1] = __builtin_amdgcn_mfma_f32_16x16x32_bf16(av0, pb1, acc2[0][1], 0, 0, 0);
            acc2[1][0] = __builtin_amdgcn_mfma_f32_16x16x32_bf16(av1, pb0, acc2[1][0], 0, 0, 0);
            acc2[1][1] = __builtin_amdgcn_mfma_f32_16x16x32_bf16(av1, pb1, acc2[1][1], 0, 0, 0);
        }
        // odd sub-step (pvB)
        {
            const int ko = kb + 1;
            *(uint4*)(smVw + lane * 8)       = pvB[0];
            *(uint4*)(smVw + 512 + lane * 8) = pvB[1];
            if (kb + 3 < 32) ldV(pvB, kb + 3);
            const int cc0 = w * 32 + l15;
            const int cc1 = w * 32 + 16 + l15;
            short8 av0 = *(const short8*)(smV + cc0 * 32 + ((quad ^ ((cc0 >> 1) & 3)) * 8));
            short8 av1 = *(const short8*)(smV + cc1 * 32 + ((quad ^ ((cc1 >> 1) & 3)) * 8));
            short8 pb0 = *(const short8*)(smP + l15 * 1024 + (((ko * 4 + quad) ^ (l15 & 7)) * 8));
            short8 pb1 = *(const short8*)(smP + (16 + l15) * 1024 + (((ko * 4 + quad) ^ (l15 & 7)) * 8));
            acc2[0][0] = __builtin_amdgcn_mfma_f32_16x16x32_bf16(av0, pb0, acc2[0][0], 0, 0, 0);
            acc2[0][1] = __builtin_amdgcn_mfma_f32_16x16x32_bf16(av0, pb1, acc2[0][1], 0, 0, 0);
            acc2[1][0] = __builtin_amdgcn_mfma_f32_16x16x32_bf16(av1, pb0, acc2[1][0], 0, 0, 0);
            acc2[1][1] = __builtin_amdgcn_mfma_f32_16x16x32_bf16(av1, pb1, acc2[1][1], 0, 0, 0);
        }
    }

#pragma unroll
    for (int mi = 0; mi < 2; ++mi) {
        const int cb = w * 32 + mi * 16 + quad * 4;
#pragma unroll
        for (int r = 0; r < 4; ++r)
#pragma unroll
            for (int ni = 0; ni < 2; ++ni)
                Rb[(size_t)(cb + r) * T_D + ni * 16 + l15] = acc2[mi][ni][r];
    }
}

// ---- final R copy: d_in[1] scratch -> real output location ----
__global__ __launch_bounds__(256) void cp_r(const float4* __restrict__ s,
                                            float4* __restrict__ d) {
    const int n = N_B * C_D * T_D / 4;
    int i = blockIdx.x * 256 + threadIdx.x;
    const int st = gridDim.x * 256;
    for (; i < n; i += st) d[i] = s[i];
}

extern "C" void kernel_launch(void* const* d_in, const int* in_sizes, int n_in,
                              void* d_out, int out_size, void* d_ws, size_t ws_size,
                              hipStream_t stream) {
    const float* Qf = (const float*)d_in[0];
    const float* Kf = (const float*)d_in[1];
    const float* Vf = (const float*)d_in[2];
    const float* Wq = (const float*)d_in[3];
    const float* bq = (const float*)d_in[4];
    const float* Wk = (const float*)d_in[5];
    const float* bk = (const float*)d_in[6];
    const float* Wv = (const float*)d_in[7];
    const float* bv = (const float*)d_in[8];

    float* Rout = (float*)d_out;
    float* Aout = Rout + (size_t)N_B * C_D * T_D;

    u16* QpT = (u16*)Rout;                 // bf16 (n,t,c) in R region
    u16* KpT = (u16*)Rout + 8388608;       // bf16 (n,s,c) in R region
    u16* Wqb = (u16*)Aout;                 // weights at head of A region (dead
    u16* Wkb = Wqb + 65536;                //   before attn_fused writes A)
    u16* Wvb = Wkb + 65536;
    u16* Vp  = (u16*)d_in[0];              // bf16 (n,c,s) — Q consumed by then
    float* Rscr = (float*)d_in[1];         // R scratch — K consumed by then

    dim3 blk(256);
    const long sX = (long)C_D * T_D;

    // 1) weights fp32 -> bf16
    conv_w<<<dim3(256, 3), blk, 0, stream>>>(Wq, Wk, Wv, Wqb, Wkb, Wvb);

    // 2) Q+K projections in ONE launch (z in [0,32) = Q, [32,64) = K)
    gemm_t<true, false, 1, true><<<dim3(2, 8, 2 * N_B), blk, 0, stream>>>(
            Qf, Wqb, bq, QpT, C_D, C_D, sX, 0, sX, 1.0f,
            Kf, Wkb, bk, KpT);
    //    V projection
    gemm_t<false, true, 2, false><<<dim3(8, 2, N_B), blk, 0, stream>>>(
            Wvb, Vf, bv, Vp, C_D, T_D, 0, sX, sX, 1.0f,
            nullptr, nullptr, nullptr, nullptr);

    // 3) fused scores + exact softmax + A write + R = Vp.A
    attn_fused<<<dim3(1024), dim3(512), 0, stream>>>(KpT, QpT, Vp, Aout, Rscr);

    // 4) move R into place (QpT/KpT dead)
    cp_r<<<dim3(2048), blk, 0, stream>>>((const float4*)Rscr, (float4*)Rout);
}